// Round 2
// baseline (15562.941 us; speedup 1.0000x reference)
//
#include <hip/hip_runtime.h>
#include <hip/hip_bf16.h>

#define BATCH 1024
#define NLAYER 19
#define DTOT 267696

struct LayerDef { int Cin,Hin,Win,Cout,Hout,Wout,stride,woff; };
static const LayerDef LD[NLAYER] = {
 { 3,32,32,16,32,32,1,0},
 {16,32,32,16,32,32,1,432},
 {16,32,32,16,32,32,1,2736},
 {16,32,32,16,32,32,1,5040},
 {16,32,32,16,32,32,1,7344},
 {16,32,32,16,32,32,1,9648},
 {16,32,32,16,32,32,1,11952},
 {16,32,32,32,16,16,2,14256},
 {32,16,16,32,16,16,1,18864},
 {32,16,16,32,16,16,1,28080},
 {32,16,16,32,16,16,1,37296},
 {32,16,16,32,16,16,1,46512},
 {32,16,16,32,16,16,1,55728},
 {32,16,16,64, 8, 8,2,64944},
 {64, 8, 8,64, 8, 8,1,83376},
 {64, 8, 8,64, 8, 8,1,120240},
 {64, 8, 8,64, 8, 8,1,157104},
 {64, 8, 8,64, 8, 8,1,193968},
 {64, 8, 8,64, 8, 8,1,230832},
};

__device__ inline float ldf(const float* p){ return *p; }
__device__ inline float ldf(const __hip_bfloat16* p){ return __bfloat162float(*p); }

// ---- dtype detector: flag=1 if x is bf16, flag=0 if x is f32 ----
// bf16 N(0,1) data: all exponent fields <= ~131. f32 data read as uint16:
// the low-half words have uniform-random exponent fields -> huge/NaN values.
__global__ void detect_kernel(const unsigned short* __restrict__ xraw, int* __restrict__ flag)
{
    __shared__ int bad;
    if (threadIdx.x == 0) bad = 0;
    __syncthreads();
    int lbad = 0;
    for (int i = threadIdx.x; i < 4096; i += 256) {
        unsigned e = (xraw[i] >> 7) & 0xFF;   // bf16 exponent field
        if (e >= 147) lbad++;                 // |v| >= 2^20 or NaN/Inf
    }
    if (lbad) atomicAdd(&bad, lbad);
    __syncthreads();
    if (threadIdx.x == 0) *flag = (bad == 0) ? 1 : 0;
}

__device__ inline bool flag_skip(const int* flag, int want)
{
    if (flag == nullptr) return false;
    return (*(volatile const int*)flag) != want;
}

// w_flat = origin + new_param @ P   (inputs T, output fp32)
template<typename T>
__global__ void wflat_kernel(const T* __restrict__ origin,
                             const T* __restrict__ P,
                             const T* __restrict__ npar,
                             float* __restrict__ wout, int D,
                             const int* flag, int want)
{
    if (flag_skip(flag, want)) return;
    int d = blockIdx.x*256 + threadIdx.x;
    if (d >= D) return;
    float acc = ldf(origin + d);
    #pragma unroll 8
    for (int k = 0; k < 40; k++)
        acc += ldf(npar + k) * ldf(P + (long long)k*D + d);
    wout[d] = acc;
}

// Direct 3x3 conv, pad=1. One thread per output element. Fused per-channel
// sum/sumsq reduction into stats[co] / stats[64+co] for the BN pass.
// Requires: blockDim divides Hout*Wout (single co per block).
template<typename T>
__global__ void conv3x3_kernel(const T* __restrict__ in, const float* __restrict__ wt,
    float* __restrict__ out, float* __restrict__ stats,
    int Cin, int Hin, int Win, int Cout, int Hout, int Wout, int stride,
    const int* flag, int want)
{
    if (flag_skip(flag, want)) return;
    extern __shared__ float sw[];
    const int tid = threadIdx.x;
    const int HW = Hout*Wout;
    const long long gidx = (long long)blockIdx.x*blockDim.x + tid;
    const int wo = (int)(gidx % Wout);
    const int ho = (int)((gidx / Wout) % Hout);
    const int plane = (int)(gidx / HW);
    const int co = plane % Cout;
    const int b  = plane / Cout;

    for (int i = tid; i < Cin*9; i += blockDim.x) sw[i] = wt[co*Cin*9 + i];
    __syncthreads();

    const T* inb = in + (long long)b*Cin*Hin*Win;
    const int ih0 = ho*stride - 1;
    const int iw0 = wo*stride - 1;
    float acc = 0.f;
    for (int ci = 0; ci < Cin; ci++) {
        const T* ip = inb + (long long)ci*Hin*Win;
        const float* wp = sw + ci*9;
        #pragma unroll
        for (int kh = 0; kh < 3; kh++) {
            int ih = ih0 + kh;
            if ((unsigned)ih < (unsigned)Hin) {
                const T* rp = ip + (long long)ih*Win;
                #pragma unroll
                for (int kw = 0; kw < 3; kw++) {
                    int iw = iw0 + kw;
                    if ((unsigned)iw < (unsigned)Win)
                        acc += ldf(rp + iw) * wp[kh*3+kw];
                }
            }
        }
    }
    out[gidx] = acc;

    // block-wide reduce of (sum, sumsq); whole block shares one co
    float s = acc, q = acc*acc;
    #pragma unroll
    for (int off = 32; off > 0; off >>= 1) {
        s += __shfl_down(s, off, 64);
        q += __shfl_down(q, off, 64);
    }
    __shared__ float red[4][2];
    const int lane = tid & 63, wid = tid >> 6;
    if (lane == 0) { red[wid][0] = s; red[wid][1] = q; }
    __syncthreads();
    if (tid == 0) {
        float S = 0.f, Q = 0.f;
        const int nw = blockDim.x >> 6;
        for (int i = 0; i < nw; i++) { S += red[i][0]; Q += red[i][1]; }
        atomicAdd(&stats[co], S);
        atomicAdd(&stats[64+co], Q);
    }
}

// y = relu((x-mean)*rsqrt(var+eps)), in-place; finalize fused (reads raw sums)
__global__ void bn_relu_kernel(float* __restrict__ x, const float* __restrict__ stats,
    int C, int HW, float invN, int n)
{
    int i = blockIdx.x*256 + threadIdx.x;
    if (i >= n) return;
    int c = (i / HW) % C;
    float m = stats[c] * invN;
    float v = fmaxf(stats[64+c] * invN - m*m, 0.f);
    x[i] = fmaxf((x[i]-m)*rsqrtf(v + 1e-5f), 0.f);
}

// y = relu(bn(x) + shortcut(prev)), in-place over x
__global__ void bn_add_relu_kernel(float* __restrict__ x, const float* __restrict__ prev,
    const float* __restrict__ stats, int C, int H, int W, int prevC, int padF, int stride,
    float invN, int n)
{
    int i = blockIdx.x*256 + threadIdx.x;
    if (i >= n) return;
    int wq = i % W;
    int hq = (i / W) % H;
    int c  = (i / (W*H)) % C;
    int b  = i / (W*H*C);
    float m = stats[c]*invN;
    float v = fmaxf(stats[64+c]*invN - m*m, 0.f);
    float val = (x[i]-m)*rsqrtf(v + 1e-5f);
    float sc = 0.f;
    if (stride == 1) {
        sc = prev[i];
    } else {
        int pc = c - padF;
        if (pc >= 0 && pc < prevC)
            sc = prev[(((long long)b*prevC + pc)*(H*2) + 2*hq)*(W*2) + 2*wq];
    }
    x[i] = fmaxf(val + sc, 0.f);
}

__device__ inline void stf(float* p, float v){ *p = v; }
__device__ inline void stf(__hip_bfloat16* p, float v){ *p = __float2bfloat16(v); }

// mean over 8x8 spatial -> (B,64); out = feat @ Wfc^T + bfc  -> (B,10)
template<typename T>
__global__ void poolfc_kernel(const float* __restrict__ in,
    const T* __restrict__ Wfc, const T* __restrict__ bfc,
    T* __restrict__ out, const int* flag, int want)
{
    if (flag_skip(flag, want)) return;
    int b = blockIdx.x;
    int c = threadIdx.x; // 64 threads
    const float* p = in + ((long long)b*64 + c)*64;
    float s = 0.f;
    #pragma unroll
    for (int i = 0; i < 64; i++) s += p[i];
    __shared__ float feat[64];
    feat[c] = s * (1.f/64.f);
    __syncthreads();
    if (c < 10) {
        float o = ldf(bfc + c);
        for (int k = 0; k < 64; k++)
            o += feat[k] * ldf(Wfc + c*64 + k);
        stf(out + b*10 + c, o);
    }
}

extern "C" void kernel_launch(void* const* d_in, const int* in_sizes, int n_in,
                              void* d_out, int out_size, void* d_ws, size_t ws_size,
                              hipStream_t stream)
{
    char* ws = (char*)d_ws;
    float* wflat = (float*)(ws);                  // DTOT floats
    float* stats = (float*)(ws + 1114112);        // 19 slots x 256 floats
    int*   flag  = (int*)  (ws + 1114112 + 32768);
    float* bufA  = (float*)(ws + 1179648);
    float* bufB  = (float*)(ws + 1179648 + 67108864);
    float* bufC  = (float*)(ws + 1179648 + 2*67108864ULL);

    // zero stats + flag region
    hipMemsetAsync(stats, 0, 65536, stream);

    detect_kernel<<<1, 256, 0, stream>>>((const unsigned short*)d_in[0], flag);

    // weight reconstruction (both dtype variants, flag-guarded)
    wflat_kernel<__hip_bfloat16><<<(DTOT+255)/256, 256, 0, stream>>>(
        (const __hip_bfloat16*)d_in[1], (const __hip_bfloat16*)d_in[2],
        (const __hip_bfloat16*)d_in[3], wflat, DTOT, flag, 1);
    wflat_kernel<float><<<(DTOT+255)/256, 256, 0, stream>>>(
        (const float*)d_in[1], (const float*)d_in[2],
        (const float*)d_in[3], wflat, DTOT, flag, 0);

    // layer 0: x -> bufA, bn+relu in place (both dtype variants)
    {
        const LayerDef& L = LD[0];
        long long n = (long long)BATCH*L.Cout*L.Hout*L.Wout;
        conv3x3_kernel<__hip_bfloat16><<<(int)(n/256), 256, L.Cin*9*sizeof(float), stream>>>(
            (const __hip_bfloat16*)d_in[0], wflat + L.woff, bufA, stats,
            L.Cin, L.Hin, L.Win, L.Cout, L.Hout, L.Wout, 1, flag, 1);
        conv3x3_kernel<float><<<(int)(n/256), 256, L.Cin*9*sizeof(float), stream>>>(
            (const float*)d_in[0], wflat + L.woff, bufA, stats,
            L.Cin, L.Hin, L.Win, L.Cout, L.Hout, L.Wout, 1, flag, 0);
        float invN = 1.f / (float)(BATCH*L.Hout*L.Wout);
        bn_relu_kernel<<<(int)((n+255)/256), 256, 0, stream>>>(
            bufA, stats, L.Cout, L.Hout*L.Wout, invN, (int)n);
    }

    static const int BL[9][4] = {{1,2,1,16},{3,4,1,16},{5,6,1,16},{7,8,2,32},
                                 {9,10,1,32},{11,12,1,32},{13,14,2,64},{15,16,1,64},{17,18,1,64}};
    float* cur = bufA;
    float* f1  = bufB;
    float* f2  = bufC;
    for (int bi = 0; bi < 9; bi++) {
        const int la = BL[bi][0], lb = BL[bi][1], s = BL[bi][2];
        const LayerDef& A  = LD[la];
        const LayerDef& Bd = LD[lb];

        long long nA = (long long)BATCH*A.Cout*A.Hout*A.Wout;
        int blkA = (A.Hout*A.Wout >= 256) ? 256 : 64;
        conv3x3_kernel<float><<<(int)(nA/blkA), blkA, A.Cin*9*sizeof(float), stream>>>(
            cur, wflat + A.woff, f1, stats + la*256,
            A.Cin, A.Hin, A.Win, A.Cout, A.Hout, A.Wout, A.stride, nullptr, 0);
        float invNA = 1.f / (float)(BATCH*A.Hout*A.Wout);
        bn_relu_kernel<<<(int)((nA+255)/256), 256, 0, stream>>>(
            f1, stats + la*256, A.Cout, A.Hout*A.Wout, invNA, (int)nA);

        long long nB = (long long)BATCH*Bd.Cout*Bd.Hout*Bd.Wout;
        int blkB = (Bd.Hout*Bd.Wout >= 256) ? 256 : 64;
        conv3x3_kernel<float><<<(int)(nB/blkB), blkB, Bd.Cin*9*sizeof(float), stream>>>(
            f1, wflat + Bd.woff, f2, stats + lb*256,
            Bd.Cin, Bd.Hin, Bd.Win, Bd.Cout, Bd.Hout, Bd.Wout, 1, nullptr, 0);
        float invNB = 1.f / (float)(BATCH*Bd.Hout*Bd.Wout);
        int padF = (s == 1) ? 0 : (BL[bi][3] - A.Cin)/2;
        bn_add_relu_kernel<<<(int)((nB+255)/256), 256, 0, stream>>>(
            f2, cur, stats + lb*256, Bd.Cout, Bd.Hout, Bd.Wout, A.Cin, padF, s, invNB, (int)nB);

        float* ncur = f2; f2 = cur; cur = ncur;
    }

    poolfc_kernel<__hip_bfloat16><<<BATCH, 64, 0, stream>>>(
        cur, (const __hip_bfloat16*)d_in[4], (const __hip_bfloat16*)d_in[5],
        (__hip_bfloat16*)d_out, flag, 1);
    poolfc_kernel<float><<<BATCH, 64, 0, stream>>>(
        cur, (const float*)d_in[4], (const float*)d_in[5],
        (float*)d_out, flag, 0);
}

// Round 3
// 3116.122 us; speedup vs baseline: 4.9943x; 4.9943x over previous
//
#include <hip/hip_runtime.h>
#include <hip/hip_bf16.h>

#define BATCH 1024
#define NLAYER 19
#define DTOT 267696

__device__ inline float ldf(const float* p){ return *p; }
__device__ inline float ldf(const __hip_bfloat16* p){ return __bfloat162float(*p); }

// ---- dtype detector (kept as insurance): flag=1 if x is bf16, 0 if f32 ----
__global__ void detect_kernel(const unsigned short* __restrict__ xraw, int* __restrict__ flag)
{
    __shared__ int bad;
    if (threadIdx.x == 0) bad = 0;
    __syncthreads();
    int lbad = 0;
    for (int i = threadIdx.x; i < 4096; i += 256) {
        unsigned e = (xraw[i] >> 7) & 0xFF;
        if (e >= 147) lbad++;
    }
    if (lbad) atomicAdd(&bad, lbad);
    __syncthreads();
    if (threadIdx.x == 0) *flag = (bad == 0) ? 1 : 0;
}

__device__ inline bool flag_skip(const int* flag, int want)
{
    if (flag == nullptr) return false;
    return (*(volatile const int*)flag) != want;
}

// w_flat = origin + new_param @ P
template<typename T>
__global__ void wflat_kernel(const T* __restrict__ origin,
                             const T* __restrict__ P,
                             const T* __restrict__ npar,
                             float* __restrict__ wout, int D,
                             const int* flag, int want)
{
    if (flag_skip(flag, want)) return;
    int d = blockIdx.x*256 + threadIdx.x;
    if (d >= D) return;
    float acc = ldf(origin + d);
    #pragma unroll 8
    for (int k = 0; k < 40; k++)
        acc += ldf(npar + k) * ldf(P + (long long)k*D + d);
    wout[d] = acc;
}

// ---- Tiled direct 3x3 conv, pad=1. One block (256 thr) per batch image. ----
// Full input image staged in LDS; weights staged in ci-chunks of CH.
// Thread layout: r = tid % HOUT (output row), g = tid / HOUT (co group of TC=2).
// Each thread computes acc[2][WOUT] (two full output rows across co).
// Fused per-channel sum/sumsq into stats[co]/stats[64+co].
template<typename T, int CIN, int COUT, int HIN, int WIN, int STRIDE, int CH>
__global__ __launch_bounds__(256, 2) void conv_tile(
    const T* __restrict__ in, const float* __restrict__ wt,
    float* __restrict__ out, float* __restrict__ stats,
    const int* flag, int want)
{
    if (flag_skip(flag, want)) return;
    constexpr int HOUT = HIN / STRIDE;
    constexpr int WOUT = WIN / STRIDE;
    constexpr int GRPS = 256 / HOUT;
    constexpr int TC   = COUT / GRPS;     // == 2 for all instantiations
    constexpr int WP   = WIN + 2;         // row pad: 2-way LDS aliasing is free

    __shared__ float in_s[CIN][HIN][WP];
    __shared__ float w_s[COUT][CH][9];

    const int tid = threadIdx.x;
    const int b   = blockIdx.x;

    // stage full input image
    const T* inb = in + (size_t)b*CIN*HIN*WIN;
    for (int i = tid; i < CIN*HIN*WIN; i += 256) {
        int w = i % WIN; int h = (i/WIN) % HIN; int c = i/(WIN*HIN);
        in_s[c][h][w] = ldf(inb + i);
    }

    const int r   = tid % HOUT;
    const int g   = tid / HOUT;
    const int co0 = g * TC;

    float acc[TC][WOUT];
    #pragma unroll
    for (int c = 0; c < TC; c++)
        #pragma unroll
        for (int wo = 0; wo < WOUT; wo++) acc[c][wo] = 0.f;

    for (int cc = 0; cc < CIN; cc += CH) {
        __syncthreads();
        for (int i = tid; i < COUT*CH*9; i += 256) {
            int k = i % 9; int c2 = (i/9) % CH; int o = i/(9*CH);
            w_s[o][c2][k] = wt[((size_t)o*CIN + cc + c2)*9 + k];
        }
        __syncthreads();

        for (int ci = 0; ci < CH; ci++) {
            #pragma unroll
            for (int kh = 0; kh < 3; kh++) {
                const int ih = r*STRIDE + kh - 1;
                float rv[WIN];
                if ((unsigned)ih < (unsigned)HIN) {
                    #pragma unroll
                    for (int w = 0; w < WIN; w++) rv[w] = in_s[cc+ci][ih][w];
                } else {
                    #pragma unroll
                    for (int w = 0; w < WIN; w++) rv[w] = 0.f;
                }
                float wv[TC][3];
                #pragma unroll
                for (int c = 0; c < TC; c++)
                    #pragma unroll
                    for (int kw = 0; kw < 3; kw++)
                        wv[c][kw] = w_s[co0+c][ci][kh*3+kw];
                #pragma unroll
                for (int c = 0; c < TC; c++)
                    #pragma unroll
                    for (int kw = 0; kw < 3; kw++)
                        #pragma unroll
                        for (int wo = 0; wo < WOUT; wo++) {
                            constexpr int dummy = 0; (void)dummy;
                            int iw = wo*STRIDE + kw - 1;
                            if (iw >= 0 && iw < WIN)
                                acc[c][wo] += rv[iw] * wv[c][kw];
                        }
            }
        }
    }

    // epilogue: store + per-co stats
    float s[TC], q[TC];
    #pragma unroll
    for (int c = 0; c < TC; c++) {
        float ss = 0.f, qq = 0.f;
        float* ob = out + (((size_t)b*COUT + co0 + c)*HOUT + r)*WOUT;
        #pragma unroll
        for (int wo = 0; wo < WOUT; wo++) {
            float v = acc[c][wo];
            ob[wo] = v;
            ss += v; qq += v*v;
        }
        s[c] = ss; q[c] = qq;
    }
    #pragma unroll
    for (int off = HOUT/2; off > 0; off >>= 1) {
        #pragma unroll
        for (int c = 0; c < TC; c++) {
            s[c] += __shfl_down(s[c], off, HOUT);
            q[c] += __shfl_down(q[c], off, HOUT);
        }
    }
    if (r == 0) {
        #pragma unroll
        for (int c = 0; c < TC; c++) {
            atomicAdd(&stats[co0+c],    s[c]);
            atomicAdd(&stats[64+co0+c], q[c]);
        }
    }
}

// y = relu((x-mean)*rsqrt(var+eps)), in-place
__global__ void bn_relu_kernel(float* __restrict__ x, const float* __restrict__ stats,
    int C, int HW, float invN, int n)
{
    int i = blockIdx.x*256 + threadIdx.x;
    if (i >= n) return;
    int c = (i / HW) % C;
    float m = stats[c] * invN;
    float v = fmaxf(stats[64+c] * invN - m*m, 0.f);
    x[i] = fmaxf((x[i]-m)*rsqrtf(v + 1e-5f), 0.f);
}

// y = relu(bn(x) + shortcut(prev)), in-place over x
__global__ void bn_add_relu_kernel(float* __restrict__ x, const float* __restrict__ prev,
    const float* __restrict__ stats, int C, int H, int W, int prevC, int padF, int stride,
    float invN, int n)
{
    int i = blockIdx.x*256 + threadIdx.x;
    if (i >= n) return;
    int wq = i % W;
    int hq = (i / W) % H;
    int c  = (i / (W*H)) % C;
    int b  = i / (W*H*C);
    float m = stats[c]*invN;
    float v = fmaxf(stats[64+c]*invN - m*m, 0.f);
    float val = (x[i]-m)*rsqrtf(v + 1e-5f);
    float sc = 0.f;
    if (stride == 1) {
        sc = prev[i];
    } else {
        int pc = c - padF;
        if (pc >= 0 && pc < prevC)
            sc = prev[(((long long)b*prevC + pc)*(H*2) + 2*hq)*(W*2) + 2*wq];
    }
    x[i] = fmaxf(val + sc, 0.f);
}

__device__ inline void stf(float* p, float v){ *p = v; }
__device__ inline void stf(__hip_bfloat16* p, float v){ *p = __float2bfloat16(v); }

// mean over 8x8 spatial -> (B,64); out = feat @ Wfc^T + bfc  -> (B,10)
template<typename T>
__global__ void poolfc_kernel(const float* __restrict__ in,
    const T* __restrict__ Wfc, const T* __restrict__ bfc,
    T* __restrict__ out, const int* flag, int want)
{
    if (flag_skip(flag, want)) return;
    int b = blockIdx.x;
    int c = threadIdx.x; // 64 threads
    const float* p = in + ((long long)b*64 + c)*64;
    float s = 0.f;
    #pragma unroll
    for (int i = 0; i < 64; i++) s += p[i];
    __shared__ float feat[64];
    feat[c] = s * (1.f/64.f);
    __syncthreads();
    if (c < 10) {
        float o = ldf(bfc + c);
        for (int k = 0; k < 64; k++)
            o += feat[k] * ldf(Wfc + c*64 + k);
        stf(out + b*10 + c, o);
    }
}

extern "C" void kernel_launch(void* const* d_in, const int* in_sizes, int n_in,
                              void* d_out, int out_size, void* d_ws, size_t ws_size,
                              hipStream_t stream)
{
    char* ws = (char*)d_ws;
    float* wflat = (float*)(ws);                  // DTOT floats
    float* stats = (float*)(ws + 1114112);        // 19 slots x 256 floats
    int*   flag  = (int*)  (ws + 1114112 + 32768);
    float* bufA  = (float*)(ws + 1179648);
    float* bufB  = (float*)(ws + 1179648 + 67108864);
    float* bufC  = (float*)(ws + 1179648 + 2*67108864ULL);

    hipMemsetAsync(stats, 0, 32768, stream);
    detect_kernel<<<1, 256, 0, stream>>>((const unsigned short*)d_in[0], flag);

    wflat_kernel<__hip_bfloat16><<<(DTOT+255)/256, 256, 0, stream>>>(
        (const __hip_bfloat16*)d_in[1], (const __hip_bfloat16*)d_in[2],
        (const __hip_bfloat16*)d_in[3], wflat, DTOT, flag, 1);
    wflat_kernel<float><<<(DTOT+255)/256, 256, 0, stream>>>(
        (const float*)d_in[1], (const float*)d_in[2],
        (const float*)d_in[3], wflat, DTOT, flag, 0);

    // weight offsets
    static const int WOFF[NLAYER] = {0,432,2736,5040,7344,9648,11952,14256,18864,
        28080,37296,46512,55728,64944,83376,120240,157104,193968,230832};

    // ---- layer 0: x -> bufA ----
    {
        long long n = (long long)BATCH*16*32*32;
        conv_tile<__hip_bfloat16,3,16,32,32,1,3><<<BATCH, 256, 0, stream>>>(
            (const __hip_bfloat16*)d_in[0], wflat + WOFF[0], bufA, stats, flag, 1);
        conv_tile<float,3,16,32,32,1,3><<<BATCH, 256, 0, stream>>>(
            (const float*)d_in[0], wflat + WOFF[0], bufA, stats, flag, 0);
        float invN = 1.f / (float)(BATCH*32*32);
        bn_relu_kernel<<<(int)((n+255)/256), 256, 0, stream>>>(bufA, stats, 16, 1024, invN, (int)n);
    }

    float* cur = bufA;
    float* f1  = bufB;
    float* f2  = bufC;

    // helper macro: conv (layer l) + bn_relu
    #define CONV_A(l, CI, CO, HI, WI, ST, CHk, src, dst) do { \
        long long n_ = (long long)BATCH*(CO)*((HI)/(ST))*((WI)/(ST)); \
        conv_tile<float,CI,CO,HI,WI,ST,CHk><<<BATCH, 256, 0, stream>>>( \
            src, wflat + WOFF[l], dst, stats + (l)*256, nullptr, 0); \
        float invN_ = 1.f / (float)(BATCH*((HI)/(ST))*((WI)/(ST))); \
        bn_relu_kernel<<<(int)((n_+255)/256), 256, 0, stream>>>( \
            dst, stats + (l)*256, CO, ((HI)/(ST))*((WI)/(ST)), invN_, (int)n_); \
    } while(0)

    #define CONV_B(l, CI, CO, HI, WI, CHk, src, dst, prevbuf, prevC, padF, sstr) do { \
        long long n_ = (long long)BATCH*(CO)*(HI)*(WI); \
        conv_tile<float,CI,CO,HI,WI,1,CHk><<<BATCH, 256, 0, stream>>>( \
            src, wflat + WOFF[l], dst, stats + (l)*256, nullptr, 0); \
        float invN_ = 1.f / (float)(BATCH*(HI)*(WI)); \
        bn_add_relu_kernel<<<(int)((n_+255)/256), 256, 0, stream>>>( \
            dst, prevbuf, stats + (l)*256, CO, HI, WI, prevC, padF, sstr, invN_, (int)n_); \
    } while(0)

    // blocks 0-2: 16ch 32x32
    for (int bi = 0; bi < 3; bi++) {
        int la = 1 + bi*2, lb = 2 + bi*2;
        CONV_A(la, 16,16,32,32,1,16, cur, f1);
        CONV_B(lb, 16,16,32,32,16, f1, f2, cur, 16, 0, 1);
        float* t = f2; f2 = cur; cur = t;
    }
    // block 3: stride2 16->32ch, 32x32 -> 16x16
    CONV_A(7, 16,32,32,32,2,8, cur, f1);
    CONV_B(8, 32,32,16,16,16, f1, f2, cur, 16, 8, 2);
    { float* t = f2; f2 = cur; cur = t; }
    // blocks 4-5: 32ch 16x16
    for (int bi = 0; bi < 2; bi++) {
        int la = 9 + bi*2, lb = 10 + bi*2;
        CONV_A(la, 32,32,16,16,1,16, cur, f1);
        CONV_B(lb, 32,32,16,16,16, f1, f2, cur, 32, 0, 1);
        float* t = f2; f2 = cur; cur = t;
    }
    // block 6: stride2 32->64ch, 16x16 -> 8x8
    CONV_A(13, 32,64,16,16,2,16, cur, f1);
    CONV_B(14, 64,64,8,8,16, f1, f2, cur, 32, 16, 2);
    { float* t = f2; f2 = cur; cur = t; }
    // blocks 7-8: 64ch 8x8
    for (int bi = 0; bi < 2; bi++) {
        int la = 15 + bi*2, lb = 16 + bi*2;
        CONV_A(la, 64,64,8,8,1,16, cur, f1);
        CONV_B(lb, 64,64,8,8,16, f1, f2, cur, 64, 0, 1);
        float* t = f2; f2 = cur; cur = t;
    }

    poolfc_kernel<__hip_bfloat16><<<BATCH, 64, 0, stream>>>(
        cur, (const __hip_bfloat16*)d_in[4], (const __hip_bfloat16*)d_in[5],
        (__hip_bfloat16*)d_out, flag, 1);
    poolfc_kernel<float><<<BATCH, 64, 0, stream>>>(
        cur, (const float*)d_in[4], (const float*)d_in[5],
        (float*)d_out, flag, 0);
}